// Round 4
// baseline (387.266 us; speedup 1.0000x reference)
//
#include <hip/hip_runtime.h>

#define N_NODES 50000
#define N_EDGES 800000
#define D_FEAT  128
#define NE_ENV  4
#define EPS_F   1e-8f
#define M_CONST 4.0f   // constant softmax shift; exact max cancels in num/denom

typedef __attribute__((ext_vector_type(8))) short bf16x8;
typedef __attribute__((ext_vector_type(4))) float floatx4;

static __device__ __forceinline__ unsigned short f2bf(float v) {
    union { float f; unsigned int u; } c; c.f = v;
    unsigned int u = c.u;
    u += 0x7fffu + ((u >> 16) & 1u);   // round-to-nearest-even
    return (unsigned short)(u >> 16);
}

static __device__ __forceinline__ float2 bf2f(unsigned int v) {
    float2 r;
    r.x = __uint_as_float(v << 16);
    r.y = __uint_as_float(v & 0xffff0000u);
    return r;
}

static __device__ __forceinline__ float lrelu_exp(float z) {
    float lk = z > 0.f ? z : 0.01f * z;
    return __expf(lk - M_CONST);
}

// Fused setup: blocks 0..127 -> b-vectors; 128..383 -> W swizzle; 384..3508 -> degree histogram.
__global__ __launch_bounds__(256) void k_setup(const float* __restrict__ weights, const float* __restrict__ a,
        float* __restrict__ b, unsigned short* __restrict__ wsw,
        const int* __restrict__ row, int* __restrict__ counts) {
    int blk = blockIdx.x;
    if (blk < 128) {
        // b[c*128+d] = sum_f W[c][d][f]*a1[c][f]; b[512 + e*128+d] likewise with a2.
        int wave = threadIdx.x >> 6, lane = threadIdx.x & 63;
        int t = blk * 4 + wave;   // 0..511
        int e = t >> 7, d = t & 127;
        float2 w2 = ((const float2*)(weights + e * 16384 + d * 128))[lane];
        float2 a1 = ((const float2*)(a + e * 256))[lane];
        float2 a2 = ((const float2*)(a + e * 256 + 128))[lane];
        float p1 = w2.x * a1.x + w2.y * a1.y;
        float p2 = w2.x * a2.x + w2.y * a2.y;
#pragma unroll
        for (int off = 32; off > 0; off >>= 1) {
            p1 += __shfl_xor(p1, off, 64);
            p2 += __shfl_xor(p2, off, 64);
        }
        if (lane == 0) {
            b[e * 128 + d] = p1;
            b[512 + e * 128 + d] = p2;
        }
    } else if (blk < 384) {
        // Pre-swizzle Wcat (512x128) to bf16 MFMA B-fragment order:
        // wsw[s*4096 + t*512 + l*8 + j] = Wcat[s*32 + (l>>4)*8 + j][t*16 + (l&15)]
        int idx = (blk - 128) * 256 + threadIdx.x;  // 0..65535
        int j = idx & 7;
        int l = (idx >> 3) & 63;
        int t = (idx >> 9) & 7;
        int s = idx >> 12;
        int k = s * 32 + (l >> 4) * 8 + j;
        int f = t * 16 + (l & 15);
        int e = k >> 7, d = k & 127;
        wsw[idx] = f2bf(weights[e * 16384 + d * 128 + f]);
    } else {
        int k = (blk - 384) * 256 + threadIdx.x;
        if (k < N_EDGES) atomicAdd(&counts[row[k]], 1);
    }
}

// MFMA scores: S = X(16x128) @ Bmat(128x8), one wave per 16 nodes. Also emits x_bf (bf16 copy of x).
__global__ __launch_bounds__(256) void k_s(const float* __restrict__ x, const float* __restrict__ b,
        float* __restrict__ s_src, float* __restrict__ s_dst, unsigned short* __restrict__ xbf) {
    int wave = threadIdx.x >> 6, lane = threadIdx.x & 63;
    int gw = blockIdx.x * 4 + wave;
    if (gw >= 3125) return;               // 3125 waves x 16 nodes = 50000 exactly
    int quad = lane >> 4, lm = lane & 15;
    int base = gw * 16;

    floatx4 acc = (floatx4){0.f, 0.f, 0.f, 0.f};
    const float* xrow = x + (size_t)(base + lm) * 128 + quad * 8;
    unsigned short* xbrow = xbf + (size_t)(base + lm) * 128 + quad * 8;

#pragma unroll
    for (int s = 0; s < 4; ++s) {
        float4 lo = *(const float4*)(xrow + s * 32);
        float4 hi = *(const float4*)(xrow + s * 32 + 4);
        bf16x8 af;
        af[0] = (short)f2bf(lo.x); af[1] = (short)f2bf(lo.y);
        af[2] = (short)f2bf(lo.z); af[3] = (short)f2bf(lo.w);
        af[4] = (short)f2bf(hi.x); af[5] = (short)f2bf(hi.y);
        af[6] = (short)f2bf(hi.z); af[7] = (short)f2bf(hi.w);
        *(bf16x8*)(xbrow + s * 32) = af;

        bf16x8 bfv = (bf16x8){0, 0, 0, 0, 0, 0, 0, 0};
        if (lm < 8) {
            const float* bp = b + lm * 128 + s * 32 + quad * 8;
            float4 b0 = *(const float4*)bp;
            float4 b1 = *(const float4*)(bp + 4);
            bfv[0] = (short)f2bf(b0.x); bfv[1] = (short)f2bf(b0.y);
            bfv[2] = (short)f2bf(b0.z); bfv[3] = (short)f2bf(b0.w);
            bfv[4] = (short)f2bf(b1.x); bfv[5] = (short)f2bf(b1.y);
            bfv[6] = (short)f2bf(b1.z); bfv[7] = (short)f2bf(b1.w);
        }
        acc = __builtin_amdgcn_mfma_f32_16x16x32_bf16(af, bfv, acc, 0, 0, 0);
    }
    // C layout: col=lm, row=quad*4+r.  cols 0..3 -> s_src env, 4..7 -> s_dst env.
    if (lm < 8) {
        float* dstp = (lm < 4) ? (s_src + (size_t)(base + quad * 4) * 4 + lm)
                               : (s_dst + (size_t)(base + quad * 4) * 4 + (lm - 4));
#pragma unroll
        for (int r = 0; r < 4; ++r) dstp[r * 4] = acc[r];
    }
}

// Single-block 1024-thread exclusive scan of counts -> offsets, cursor.
__global__ __launch_bounds__(1024) void k_scan(const int* __restrict__ counts,
        int* __restrict__ offsets, int* __restrict__ cursor) {
    __shared__ int sums[1024];
    const int per = 49;   // 1024*49 = 50176 >= 50000
    int t = threadIdx.x;
    int base = t * per;
    int s = 0;
    for (int j = 0; j < per; ++j) {
        int idx = base + j;
        if (idx < N_NODES) s += counts[idx];
    }
    sums[t] = s;
    __syncthreads();
    for (int st = 1; st < 1024; st <<= 1) {
        int add = (t >= st) ? sums[t - st] : 0;
        __syncthreads();
        sums[t] += add;
        __syncthreads();
    }
    int prefix = sums[t] - s;   // exclusive
    for (int j = 0; j < per; ++j) {
        int idx = base + j;
        if (idx < N_NODES) {
            offsets[idx] = prefix;
            cursor[idx] = prefix;
            prefix += counts[idx];
        }
    }
    if (t == 0) offsets[N_NODES] = N_EDGES;
}

// Scatter ONLY the edge index (4B; target fits in L2, partial lines coalesce before writeback).
__global__ __launch_bounds__(256) void k_scatter(const int* __restrict__ row,
        int* __restrict__ cursor, int* __restrict__ sorted_k) {
    int k = blockIdx.x * blockDim.x + threadIdx.x;
    if (k < N_EDGES) {
        int pos = atomicAdd(&cursor[row[k]], 1);
        sorted_k[pos] = k;
    }
}

// Coalesced pass: read sorted_k sequentially, gather (L2-hot) metadata, compute weights,
// write sorted_dst + w_sorted SEQUENTIALLY.
__global__ __launch_bounds__(256) void k_wsort(const int* __restrict__ sorted_k,
        const int* __restrict__ row, const int* __restrict__ col,
        const float* __restrict__ s_src, const float* __restrict__ s_dst,
        int* __restrict__ sorted_dst, float4* __restrict__ w_sorted) {
    int i = blockIdx.x * blockDim.x + threadIdx.x;
    if (i >= N_EDGES) return;
    int k = sorted_k[i];
    int s = row[k], d = col[k];
    float4 a4 = *(const float4*)(s_src + s * 4);
    float4 b4 = *(const float4*)(s_dst + d * 4);
    float4 w;
    w.x = lrelu_exp(a4.x + b4.x);
    w.y = lrelu_exp(a4.y + b4.y);
    w.z = lrelu_exp(a4.z + b4.z);
    w.w = lrelu_exp(a4.w + b4.w);
    sorted_dst[i] = d;
    w_sorted[i] = w;
}

// Per-node aggregation: bf16 x gathers (4B/lane), wave-uniform scalar loads for (dst,w4), unroll-4.
__global__ __launch_bounds__(256) void k_agg(const unsigned int* __restrict__ xb,
        const float* __restrict__ s_src, const float* __restrict__ s_dst,
        const int* __restrict__ offsets, const int* __restrict__ sorted_dst,
        const float4* __restrict__ w_sorted, const float* __restrict__ env_w,
        unsigned short* __restrict__ Gp) {
    int wave = threadIdx.x >> 6, lane = threadIdx.x & 63;
    int n = blockIdx.x * 4 + wave;
    if (n >= N_NODES) return;

    float den[4], ax[4], ay[4];

    // self loop (dst = n)
    {
        float4 sa = *(const float4*)(s_src + n * 4);
        float4 sb = *(const float4*)(s_dst + n * 4);
        float ws[4] = { lrelu_exp(sa.x + sb.x), lrelu_exp(sa.y + sb.y),
                        lrelu_exp(sa.z + sb.z), lrelu_exp(sa.w + sb.w) };
        float2 xv = bf2f(xb[(size_t)n * 64 + lane]);
#pragma unroll
        for (int e = 0; e < 4; ++e) {
            den[e] = ws[e]; ax[e] = ws[e] * xv.x; ay[e] = ws[e] * xv.y;
        }
    }

    int beg = __builtin_amdgcn_readfirstlane(offsets[n]);
    int end = __builtin_amdgcn_readfirstlane(offsets[n + 1]);
    int i = beg;
    for (; i + 3 < end; i += 4) {
        int d0 = sorted_dst[i],     d1 = sorted_dst[i + 1];
        int d2 = sorted_dst[i + 2], d3 = sorted_dst[i + 3];
        float4 w0 = w_sorted[i],     w1 = w_sorted[i + 1];
        float4 w2 = w_sorted[i + 2], w3 = w_sorted[i + 3];
        unsigned int v0 = xb[(size_t)d0 * 64 + lane];
        unsigned int v1 = xb[(size_t)d1 * 64 + lane];
        unsigned int v2 = xb[(size_t)d2 * 64 + lane];
        unsigned int v3 = xb[(size_t)d3 * 64 + lane];
        float2 x0 = bf2f(v0), x1 = bf2f(v1), x2v = bf2f(v2), x3 = bf2f(v3);
        den[0] += (w0.x + w1.x) + (w2.x + w3.x);
        den[1] += (w0.y + w1.y) + (w2.y + w3.y);
        den[2] += (w0.z + w1.z) + (w2.z + w3.z);
        den[3] += (w0.w + w1.w) + (w2.w + w3.w);
        ax[0] += w0.x * x0.x + w1.x * x1.x + w2.x * x2v.x + w3.x * x3.x;
        ay[0] += w0.x * x0.y + w1.x * x1.y + w2.x * x2v.y + w3.x * x3.y;
        ax[1] += w0.y * x0.x + w1.y * x1.x + w2.y * x2v.x + w3.y * x3.x;
        ay[1] += w0.y * x0.y + w1.y * x1.y + w2.y * x2v.y + w3.y * x3.y;
        ax[2] += w0.z * x0.x + w1.z * x1.x + w2.z * x2v.x + w3.z * x3.x;
        ay[2] += w0.z * x0.y + w1.z * x1.y + w2.z * x2v.y + w3.z * x3.y;
        ax[3] += w0.w * x0.x + w1.w * x1.x + w2.w * x2v.x + w3.w * x3.x;
        ay[3] += w0.w * x0.y + w1.w * x1.y + w2.w * x2v.y + w3.w * x3.y;
    }
    for (; i < end; ++i) {
        int d0 = sorted_dst[i];
        float4 w0 = w_sorted[i];
        float2 x0 = bf2f(xb[(size_t)d0 * 64 + lane]);
        den[0] += w0.x; den[1] += w0.y; den[2] += w0.z; den[3] += w0.w;
        ax[0] += w0.x * x0.x; ay[0] += w0.x * x0.y;
        ax[1] += w0.y * x0.x; ay[1] += w0.y * x0.y;
        ax[2] += w0.z * x0.x; ay[2] += w0.z * x0.y;
        ax[3] += w0.w * x0.x; ay[3] += w0.w * x0.y;
    }

    float4 ewt = *(const float4*)(env_w + n * 4);
    float ewv[4] = { ewt.x, ewt.y, ewt.z, ewt.w };
    unsigned int* grow = (unsigned int*)(Gp + (size_t)n * 512);
#pragma unroll
    for (int e = 0; e < 4; ++e) {
        float sc = ewv[e] / (den[e] + EPS_F);
        unsigned int lo = f2bf(sc * ax[e]);
        unsigned int hi = f2bf(sc * ay[e]);
        grow[e * 64 + lane] = (hi << 16) | lo;
    }
}

// out = G'(N x 512, bf16) @ Wcat(512 x 128, bf16 pre-swizzled) + x.  One wave = 16 rows x 128 cols.
__global__ __launch_bounds__(256) void k_gemm(const unsigned short* __restrict__ Gp,
        const unsigned short* __restrict__ Wsw,
        const float* __restrict__ x, float* __restrict__ out) {
    int wave = threadIdx.x >> 6, lane = threadIdx.x & 63;
    int gw = blockIdx.x * 4 + wave;
    if (gw >= 3125) return;
    int quad = lane >> 4, lm = lane & 15;
    int m = gw * 16 + lm;

    floatx4 acc[8];
#pragma unroll
    for (int t = 0; t < 8; ++t) acc[t] = (floatx4){0.f, 0.f, 0.f, 0.f};

    const unsigned short* Arow = Gp + (size_t)m * 512 + quad * 8;
#pragma unroll
    for (int s = 0; s < 16; ++s) {
        bf16x8 af = *(const bf16x8*)(Arow + s * 32);
#pragma unroll
        for (int t = 0; t < 8; ++t) {
            bf16x8 bfv = *(const bf16x8*)(Wsw + (((s * 8 + t) * 64 + lane) * 8));
            acc[t] = __builtin_amdgcn_mfma_f32_16x16x32_bf16(af, bfv, acc[t], 0, 0, 0);
        }
    }
    int row_base = gw * 16 + quad * 4;
#pragma unroll
    for (int t = 0; t < 8; ++t) {
        int colc = t * 16 + lm;
#pragma unroll
        for (int r = 0; r < 4; ++r) {
            int rowi = row_base + r;
            out[rowi * 128 + colc] = acc[t][r] + x[rowi * 128 + colc];
        }
    }
}

extern "C" void kernel_launch(void* const* d_in, const int* in_sizes, int n_in,
                              void* d_out, int out_size, void* d_ws, size_t ws_size,
                              hipStream_t stream) {
    const float* x       = (const float*)d_in[0];
    const int*   adj     = (const int*)d_in[1];
    const int*   row     = adj;
    const int*   col     = adj + N_EDGES;
    const float* env_w   = (const float*)d_in[2];
    const float* weights = (const float*)d_in[3];
    const float* a       = (const float*)d_in[4];
    float* out = (float*)d_out;

    char* ws = (char*)d_ws;
    size_t off = 0;
    auto alloc = [&](size_t bytes) -> char* {
        char* p = ws + off;
        off += (bytes + 255) & ~(size_t)255;
        return p;
    };
    float* b          = (float*)alloc(1024 * 4);
    float* s_src      = (float*)alloc((size_t)N_NODES * 4 * 4);
    float* s_dst      = (float*)alloc((size_t)N_NODES * 4 * 4);
    int*   counts     = (int*)alloc((size_t)N_NODES * 4);
    int*   offsets    = (int*)alloc((size_t)(N_NODES + 1) * 4);
    int*   cursor     = (int*)alloc((size_t)N_NODES * 4);
    int*   sorted_k   = (int*)alloc((size_t)N_EDGES * 4);
    int*   sorted_dst = (int*)alloc((size_t)N_EDGES * 4);
    float4* w_sorted  = (float4*)alloc((size_t)N_EDGES * 16);
    unsigned short* wsw = (unsigned short*)alloc(65536 * 2);
    unsigned short* xbf = (unsigned short*)alloc((size_t)N_NODES * 128 * 2);
    unsigned short* Gp  = (unsigned short*)alloc((size_t)N_NODES * 512 * 2);

    hipMemsetAsync(counts, 0, (size_t)N_NODES * 4, stream);
    k_setup<<<3509, 256, 0, stream>>>(weights, a, b, wsw, row, counts);
    k_s<<<782, 256, 0, stream>>>(x, b, s_src, s_dst, xbf);
    k_scan<<<1, 1024, 0, stream>>>(counts, offsets, cursor);
    k_scatter<<<3125, 256, 0, stream>>>(row, cursor, sorted_k);
    k_wsort<<<3125, 256, 0, stream>>>(sorted_k, row, col, s_src, s_dst, sorted_dst, w_sorted);
    k_agg<<<12500, 256, 0, stream>>>((const unsigned int*)xbf, s_src, s_dst, offsets, sorted_dst, w_sorted, env_w, Gp);
    k_gemm<<<782, 256, 0, stream>>>(Gp, wsw, x, out);
}

// Round 5
// 272.975 us; speedup vs baseline: 1.4187x; 1.4187x over previous
//
#include <hip/hip_runtime.h>

#define N_NODES 50000
#define N_EDGES 800000
#define D_FEAT  128
#define NE_ENV  4
#define EPS_F   1e-8f
#define M_CONST 4.0f   // constant softmax shift; exact max cancels in num/denom
#define SCAN_NB 196    // ceil(50000/256)

typedef __attribute__((ext_vector_type(8))) short bf16x8;
typedef __attribute__((ext_vector_type(4))) float floatx4;

static __device__ __forceinline__ unsigned short f2bf(float v) {
    union { float f; unsigned int u; } c; c.f = v;
    unsigned int u = c.u;
    u += 0x7fffu + ((u >> 16) & 1u);   // round-to-nearest-even
    return (unsigned short)(u >> 16);
}

static __device__ __forceinline__ float2 bf2f(unsigned int v) {
    float2 r;
    r.x = __uint_as_float(v << 16);
    r.y = __uint_as_float(v & 0xffff0000u);
    return r;
}

static __device__ __forceinline__ float lrelu_exp(float z) {
    float lk = z > 0.f ? z : 0.01f * z;
    return __expf(lk - M_CONST);
}

// Fused setup: blocks 0..127 -> b-vectors; 128..383 -> W swizzle; 384..3508 -> degree histogram.
__global__ __launch_bounds__(256) void k_setup(const float* __restrict__ weights, const float* __restrict__ a,
        float* __restrict__ b, unsigned short* __restrict__ wsw,
        const int* __restrict__ row, int* __restrict__ counts) {
    int blk = blockIdx.x;
    if (blk < 128) {
        // b[c*128+d] = sum_f W[c][d][f]*a1[c][f]; b[512 + e*128+d] likewise with a2.
        int wave = threadIdx.x >> 6, lane = threadIdx.x & 63;
        int t = blk * 4 + wave;   // 0..511
        int e = t >> 7, d = t & 127;
        float2 w2 = ((const float2*)(weights + e * 16384 + d * 128))[lane];
        float2 a1 = ((const float2*)(a + e * 256))[lane];
        float2 a2 = ((const float2*)(a + e * 256 + 128))[lane];
        float p1 = w2.x * a1.x + w2.y * a1.y;
        float p2 = w2.x * a2.x + w2.y * a2.y;
#pragma unroll
        for (int off = 32; off > 0; off >>= 1) {
            p1 += __shfl_xor(p1, off, 64);
            p2 += __shfl_xor(p2, off, 64);
        }
        if (lane == 0) {
            b[e * 128 + d] = p1;
            b[512 + e * 128 + d] = p2;
        }
    } else if (blk < 384) {
        // Pre-swizzle Wcat (512x128) to bf16 MFMA B-fragment order:
        // wsw[s*4096 + t*512 + l*8 + j] = Wcat[s*32 + (l>>4)*8 + j][t*16 + (l&15)]
        int idx = (blk - 128) * 256 + threadIdx.x;  // 0..65535
        int j = idx & 7;
        int l = (idx >> 3) & 63;
        int t = (idx >> 9) & 7;
        int s = idx >> 12;
        int k = s * 32 + (l >> 4) * 8 + j;
        int f = t * 16 + (l & 15);
        int e = k >> 7, d = k & 127;
        wsw[idx] = f2bf(weights[e * 16384 + d * 128 + f]);
    } else {
        int k = (blk - 384) * 256 + threadIdx.x;
        if (k < N_EDGES) atomicAdd(&counts[row[k]], 1);
    }
}

// MFMA scores: S = X(16x128) @ Bmat(128x8), one wave per 16 nodes. Also emits x_bf (bf16 copy of x).
__global__ __launch_bounds__(256) void k_s(const float* __restrict__ x, const float* __restrict__ b,
        float* __restrict__ s_src, float* __restrict__ s_dst, unsigned short* __restrict__ xbf) {
    int wave = threadIdx.x >> 6, lane = threadIdx.x & 63;
    int gw = blockIdx.x * 4 + wave;
    if (gw >= 3125) return;               // 3125 waves x 16 nodes = 50000 exactly
    int quad = lane >> 4, lm = lane & 15;
    int base = gw * 16;

    floatx4 acc = (floatx4){0.f, 0.f, 0.f, 0.f};
    const float* xrow = x + (size_t)(base + lm) * 128 + quad * 8;
    unsigned short* xbrow = xbf + (size_t)(base + lm) * 128 + quad * 8;

#pragma unroll
    for (int s = 0; s < 4; ++s) {
        float4 lo = *(const float4*)(xrow + s * 32);
        float4 hi = *(const float4*)(xrow + s * 32 + 4);
        bf16x8 af;
        af[0] = (short)f2bf(lo.x); af[1] = (short)f2bf(lo.y);
        af[2] = (short)f2bf(lo.z); af[3] = (short)f2bf(lo.w);
        af[4] = (short)f2bf(hi.x); af[5] = (short)f2bf(hi.y);
        af[6] = (short)f2bf(hi.z); af[7] = (short)f2bf(hi.w);
        *(bf16x8*)(xbrow + s * 32) = af;

        bf16x8 bfv = (bf16x8){0, 0, 0, 0, 0, 0, 0, 0};
        if (lm < 8) {
            const float* bp = b + lm * 128 + s * 32 + quad * 8;
            float4 b0 = *(const float4*)bp;
            float4 b1 = *(const float4*)(bp + 4);
            bfv[0] = (short)f2bf(b0.x); bfv[1] = (short)f2bf(b0.y);
            bfv[2] = (short)f2bf(b0.z); bfv[3] = (short)f2bf(b0.w);
            bfv[4] = (short)f2bf(b1.x); bfv[5] = (short)f2bf(b1.y);
            bfv[6] = (short)f2bf(b1.z); bfv[7] = (short)f2bf(b1.w);
        }
        acc = __builtin_amdgcn_mfma_f32_16x16x32_bf16(af, bfv, acc, 0, 0, 0);
    }
    // C layout: col=lm, row=quad*4+r.  cols 0..3 -> s_src env, 4..7 -> s_dst env.
    if (lm < 8) {
        float* dstp = (lm < 4) ? (s_src + (size_t)(base + quad * 4) * 4 + lm)
                               : (s_dst + (size_t)(base + quad * 4) * 4 + (lm - 4));
#pragma unroll
        for (int r = 0; r < 4; ++r) dstp[r * 4] = acc[r];
    }
}

// 3-dispatch scan (proven fast): per-block sums -> scan of block sums -> per-element scan.
__global__ void k_scan_a(const int* __restrict__ counts, int* __restrict__ partial) {
    __shared__ int sm[256];
    int idx = blockIdx.x * 256 + threadIdx.x;
    sm[threadIdx.x] = (idx < N_NODES) ? counts[idx] : 0;
    __syncthreads();
    for (int s = 128; s > 0; s >>= 1) {
        if (threadIdx.x < s) sm[threadIdx.x] += sm[threadIdx.x + s];
        __syncthreads();
    }
    if (threadIdx.x == 0) partial[blockIdx.x] = sm[0];
}

__global__ void k_scan_b(const int* __restrict__ partial, int* __restrict__ chunk_off) {
    __shared__ int sm[256];
    int t = threadIdx.x;
    int v = (t < SCAN_NB) ? partial[t] : 0;
    sm[t] = v;
    __syncthreads();
    for (int s2 = 1; s2 < 256; s2 <<= 1) {
        int add = (t >= s2) ? sm[t - s2] : 0;
        __syncthreads();
        sm[t] += add;
        __syncthreads();
    }
    chunk_off[t] = sm[t] - v;   // exclusive
}

__global__ void k_scan_c(const int* __restrict__ counts, const int* __restrict__ chunk_off,
                         int* __restrict__ offsets, int* __restrict__ cursor) {
    __shared__ int sm[256];
    int t = threadIdx.x;
    int idx = blockIdx.x * 256 + t;
    int v = (idx < N_NODES) ? counts[idx] : 0;
    sm[t] = v;
    __syncthreads();
    for (int s2 = 1; s2 < 256; s2 <<= 1) {
        int add = (t >= s2) ? sm[t - s2] : 0;
        __syncthreads();
        sm[t] += add;
        __syncthreads();
    }
    if (idx < N_NODES) {
        int excl = chunk_off[blockIdx.x] + sm[t] - v;
        offsets[idx] = excl;
        cursor[idx] = excl;
    }
    if (idx == 0) offsets[N_NODES] = N_EDGES;
}

// Scatter ONLY the edge index (4B; target fits in L2, partial lines coalesce before writeback).
__global__ __launch_bounds__(256) void k_scatter(const int* __restrict__ row,
        int* __restrict__ cursor, int* __restrict__ sorted_k) {
    int k = blockIdx.x * blockDim.x + threadIdx.x;
    if (k < N_EDGES) {
        int pos = atomicAdd(&cursor[row[k]], 1);
        sorted_k[pos] = k;
    }
}

// Coalesced pass: read sorted_k sequentially, gather (L2-hot) metadata, compute weights,
// write sorted_dst + w_sorted SEQUENTIALLY.
__global__ __launch_bounds__(256) void k_wsort(const int* __restrict__ sorted_k,
        const int* __restrict__ row, const int* __restrict__ col,
        const float* __restrict__ s_src, const float* __restrict__ s_dst,
        int* __restrict__ sorted_dst, float4* __restrict__ w_sorted) {
    int i = blockIdx.x * blockDim.x + threadIdx.x;
    if (i >= N_EDGES) return;
    int k = sorted_k[i];
    int s = row[k], d = col[k];
    float4 a4 = *(const float4*)(s_src + s * 4);
    float4 b4 = *(const float4*)(s_dst + d * 4);
    float4 w;
    w.x = lrelu_exp(a4.x + b4.x);
    w.y = lrelu_exp(a4.y + b4.y);
    w.z = lrelu_exp(a4.z + b4.z);
    w.w = lrelu_exp(a4.w + b4.w);
    sorted_dst[i] = d;
    w_sorted[i] = w;
}

// Per-node aggregation: bf16 x gathers (4B/lane), wave-uniform scalar loads for (dst,w4), unroll-4.
__global__ __launch_bounds__(256) void k_agg(const unsigned int* __restrict__ xb,
        const float* __restrict__ s_src, const float* __restrict__ s_dst,
        const int* __restrict__ offsets, const int* __restrict__ sorted_dst,
        const float4* __restrict__ w_sorted, const float* __restrict__ env_w,
        unsigned short* __restrict__ Gp) {
    int wave = threadIdx.x >> 6, lane = threadIdx.x & 63;
    int n = blockIdx.x * 4 + wave;
    if (n >= N_NODES) return;

    float den[4], ax[4], ay[4];

    // self loop (dst = n)
    {
        float4 sa = *(const float4*)(s_src + n * 4);
        float4 sb = *(const float4*)(s_dst + n * 4);
        float ws[4] = { lrelu_exp(sa.x + sb.x), lrelu_exp(sa.y + sb.y),
                        lrelu_exp(sa.z + sb.z), lrelu_exp(sa.w + sb.w) };
        float2 xv = bf2f(xb[(size_t)n * 64 + lane]);
#pragma unroll
        for (int e = 0; e < 4; ++e) {
            den[e] = ws[e]; ax[e] = ws[e] * xv.x; ay[e] = ws[e] * xv.y;
        }
    }

    int beg = __builtin_amdgcn_readfirstlane(offsets[n]);
    int end = __builtin_amdgcn_readfirstlane(offsets[n + 1]);
    int i = beg;
    for (; i + 3 < end; i += 4) {
        int d0 = sorted_dst[i],     d1 = sorted_dst[i + 1];
        int d2 = sorted_dst[i + 2], d3 = sorted_dst[i + 3];
        float4 w0 = w_sorted[i],     w1 = w_sorted[i + 1];
        float4 w2 = w_sorted[i + 2], w3 = w_sorted[i + 3];
        unsigned int v0 = xb[(size_t)d0 * 64 + lane];
        unsigned int v1 = xb[(size_t)d1 * 64 + lane];
        unsigned int v2 = xb[(size_t)d2 * 64 + lane];
        unsigned int v3 = xb[(size_t)d3 * 64 + lane];
        float2 x0 = bf2f(v0), x1 = bf2f(v1), x2v = bf2f(v2), x3 = bf2f(v3);
        den[0] += (w0.x + w1.x) + (w2.x + w3.x);
        den[1] += (w0.y + w1.y) + (w2.y + w3.y);
        den[2] += (w0.z + w1.z) + (w2.z + w3.z);
        den[3] += (w0.w + w1.w) + (w2.w + w3.w);
        ax[0] += w0.x * x0.x + w1.x * x1.x + w2.x * x2v.x + w3.x * x3.x;
        ay[0] += w0.x * x0.y + w1.x * x1.y + w2.x * x2v.y + w3.x * x3.y;
        ax[1] += w0.y * x0.x + w1.y * x1.x + w2.y * x2v.x + w3.y * x3.x;
        ay[1] += w0.y * x0.y + w1.y * x1.y + w2.y * x2v.y + w3.y * x3.y;
        ax[2] += w0.z * x0.x + w1.z * x1.x + w2.z * x2v.x + w3.z * x3.x;
        ay[2] += w0.z * x0.y + w1.z * x1.y + w2.z * x2v.y + w3.z * x3.y;
        ax[3] += w0.w * x0.x + w1.w * x1.x + w2.w * x2v.x + w3.w * x3.x;
        ay[3] += w0.w * x0.y + w1.w * x1.y + w2.w * x2v.y + w3.w * x3.y;
    }
    for (; i < end; ++i) {
        int d0 = sorted_dst[i];
        float4 w0 = w_sorted[i];
        float2 x0 = bf2f(xb[(size_t)d0 * 64 + lane]);
        den[0] += w0.x; den[1] += w0.y; den[2] += w0.z; den[3] += w0.w;
        ax[0] += w0.x * x0.x; ay[0] += w0.x * x0.y;
        ax[1] += w0.y * x0.x; ay[1] += w0.y * x0.y;
        ax[2] += w0.z * x0.x; ay[2] += w0.z * x0.y;
        ax[3] += w0.w * x0.x; ay[3] += w0.w * x0.y;
    }

    float4 ewt = *(const float4*)(env_w + n * 4);
    float ewv[4] = { ewt.x, ewt.y, ewt.z, ewt.w };
    unsigned int* grow = (unsigned int*)(Gp + (size_t)n * 512);
#pragma unroll
    for (int e = 0; e < 4; ++e) {
        float sc = ewv[e] / (den[e] + EPS_F);
        unsigned int lo = f2bf(sc * ax[e]);
        unsigned int hi = f2bf(sc * ay[e]);
        grow[e * 64 + lane] = (hi << 16) | lo;
    }
}

// out = G'(N x 512, bf16) @ Wcat(512 x 128, bf16 pre-swizzled) + x.  One wave = 16 rows x 128 cols.
__global__ __launch_bounds__(256) void k_gemm(const unsigned short* __restrict__ Gp,
        const unsigned short* __restrict__ Wsw,
        const float* __restrict__ x, float* __restrict__ out) {
    int wave = threadIdx.x >> 6, lane = threadIdx.x & 63;
    int gw = blockIdx.x * 4 + wave;
    if (gw >= 3125) return;
    int quad = lane >> 4, lm = lane & 15;
    int m = gw * 16 + lm;

    floatx4 acc[8];
#pragma unroll
    for (int t = 0; t < 8; ++t) acc[t] = (floatx4){0.f, 0.f, 0.f, 0.f};

    const unsigned short* Arow = Gp + (size_t)m * 512 + quad * 8;
#pragma unroll
    for (int s = 0; s < 16; ++s) {
        bf16x8 af = *(const bf16x8*)(Arow + s * 32);
#pragma unroll
        for (int t = 0; t < 8; ++t) {
            bf16x8 bfv = *(const bf16x8*)(Wsw + (((s * 8 + t) * 64 + lane) * 8));
            acc[t] = __builtin_amdgcn_mfma_f32_16x16x32_bf16(af, bfv, acc[t], 0, 0, 0);
        }
    }
    int row_base = gw * 16 + quad * 4;
#pragma unroll
    for (int t = 0; t < 8; ++t) {
        int colc = t * 16 + lm;
#pragma unroll
        for (int r = 0; r < 4; ++r) {
            int rowi = row_base + r;
            out[rowi * 128 + colc] = acc[t][r] + x[rowi * 128 + colc];
        }
    }
}

extern "C" void kernel_launch(void* const* d_in, const int* in_sizes, int n_in,
                              void* d_out, int out_size, void* d_ws, size_t ws_size,
                              hipStream_t stream) {
    const float* x       = (const float*)d_in[0];
    const int*   adj     = (const int*)d_in[1];
    const int*   row     = adj;
    const int*   col     = adj + N_EDGES;
    const float* env_w   = (const float*)d_in[2];
    const float* weights = (const float*)d_in[3];
    const float* a       = (const float*)d_in[4];
    float* out = (float*)d_out;

    char* ws = (char*)d_ws;
    size_t off = 0;
    auto alloc = [&](size_t bytes) -> char* {
        char* p = ws + off;
        off += (bytes + 255) & ~(size_t)255;
        return p;
    };
    float* b          = (float*)alloc(1024 * 4);
    float* s_src      = (float*)alloc((size_t)N_NODES * 4 * 4);
    float* s_dst      = (float*)alloc((size_t)N_NODES * 4 * 4);
    int*   counts     = (int*)alloc((size_t)N_NODES * 4);
    int*   offsets    = (int*)alloc((size_t)(N_NODES + 1) * 4);
    int*   cursor     = (int*)alloc((size_t)N_NODES * 4);
    int*   partial    = (int*)alloc(256 * 4);
    int*   chunk_off  = (int*)alloc(256 * 4);
    int*   sorted_k   = (int*)alloc((size_t)N_EDGES * 4);
    int*   sorted_dst = (int*)alloc((size_t)N_EDGES * 4);
    float4* w_sorted  = (float4*)alloc((size_t)N_EDGES * 16);
    unsigned short* wsw = (unsigned short*)alloc(65536 * 2);
    unsigned short* xbf = (unsigned short*)alloc((size_t)N_NODES * 128 * 2);
    unsigned short* Gp  = (unsigned short*)alloc((size_t)N_NODES * 512 * 2);

    hipMemsetAsync(counts, 0, (size_t)N_NODES * 4, stream);
    k_setup<<<3509, 256, 0, stream>>>(weights, a, b, wsw, row, counts);
    k_s<<<782, 256, 0, stream>>>(x, b, s_src, s_dst, xbf);
    k_scan_a<<<SCAN_NB, 256, 0, stream>>>(counts, partial);
    k_scan_b<<<1, 256, 0, stream>>>(partial, chunk_off);
    k_scan_c<<<SCAN_NB, 256, 0, stream>>>(counts, chunk_off, offsets, cursor);
    k_scatter<<<3125, 256, 0, stream>>>(row, cursor, sorted_k);
    k_wsort<<<3125, 256, 0, stream>>>(sorted_k, row, col, s_src, s_dst, sorted_dst, w_sorted);
    k_agg<<<12500, 256, 0, stream>>>((const unsigned int*)xbf, s_src, s_dst, offsets, sorted_dst, w_sorted, env_w, Gp);
    k_gemm<<<782, 256, 0, stream>>>(Gp, wsw, x, out);
}

// Round 6
// 231.552 us; speedup vs baseline: 1.6725x; 1.1789x over previous
//
#include <hip/hip_runtime.h>

#define N_NODES 50000
#define N_EDGES 800000
#define D_FEAT  128
#define NE_ENV  4
#define EPS_F   1e-8f
#define M_CONST 4.0f   // constant softmax shift; exact max cancels in num/denom
#define SCAN_NB 196    // ceil(50000/256)
#define NB_BUCKET 391  // ceil(50000/128) src-buckets of 128 nodes
#define BINA_EPT 16    // edges per thread in k_binA

typedef __attribute__((ext_vector_type(8))) short bf16x8;
typedef __attribute__((ext_vector_type(4))) float floatx4;

static __device__ __forceinline__ unsigned short f2bf(float v) {
    union { float f; unsigned int u; } c; c.f = v;
    unsigned int u = c.u;
    u += 0x7fffu + ((u >> 16) & 1u);   // round-to-nearest-even
    return (unsigned short)(u >> 16);
}

static __device__ __forceinline__ float2 bf2f(unsigned int v) {
    float2 r;
    r.x = __uint_as_float(v << 16);
    r.y = __uint_as_float(v & 0xffff0000u);
    return r;
}

static __device__ __forceinline__ float lrelu_exp(float z) {
    float lk = z > 0.f ? z : 0.01f * z;
    return __expf(lk - M_CONST);
}

// Fused setup: blocks 0..127 -> b-vectors; 128..383 -> W swizzle; 384..3508 -> degree histogram.
__global__ __launch_bounds__(256) void k_setup(const float* __restrict__ weights, const float* __restrict__ a,
        float* __restrict__ b, unsigned short* __restrict__ wsw,
        const int* __restrict__ row, int* __restrict__ counts) {
    int blk = blockIdx.x;
    if (blk < 128) {
        int wave = threadIdx.x >> 6, lane = threadIdx.x & 63;
        int t = blk * 4 + wave;   // 0..511
        int e = t >> 7, d = t & 127;
        float2 w2 = ((const float2*)(weights + e * 16384 + d * 128))[lane];
        float2 a1 = ((const float2*)(a + e * 256))[lane];
        float2 a2 = ((const float2*)(a + e * 256 + 128))[lane];
        float p1 = w2.x * a1.x + w2.y * a1.y;
        float p2 = w2.x * a2.x + w2.y * a2.y;
#pragma unroll
        for (int off = 32; off > 0; off >>= 1) {
            p1 += __shfl_xor(p1, off, 64);
            p2 += __shfl_xor(p2, off, 64);
        }
        if (lane == 0) {
            b[e * 128 + d] = p1;
            b[512 + e * 128 + d] = p2;
        }
    } else if (blk < 384) {
        // wsw[s*4096 + t*512 + l*8 + j] = Wcat[s*32 + (l>>4)*8 + j][t*16 + (l&15)]
        int idx = (blk - 128) * 256 + threadIdx.x;  // 0..65535
        int j = idx & 7;
        int l = (idx >> 3) & 63;
        int t = (idx >> 9) & 7;
        int s = idx >> 12;
        int k = s * 32 + (l >> 4) * 8 + j;
        int f = t * 16 + (l & 15);
        int e = k >> 7, d = k & 127;
        wsw[idx] = f2bf(weights[e * 16384 + d * 128 + f]);
    } else {
        int k = (blk - 384) * 256 + threadIdx.x;
        if (k < N_EDGES) atomicAdd(&counts[row[k]], 1);
    }
}

// MFMA scores: S = X(16x128) @ Bmat(128x8), one wave per 16 nodes. Also emits x_bf (bf16 copy of x).
__global__ __launch_bounds__(256) void k_s(const float* __restrict__ x, const float* __restrict__ b,
        float* __restrict__ s_src, float* __restrict__ s_dst, unsigned short* __restrict__ xbf) {
    int wave = threadIdx.x >> 6, lane = threadIdx.x & 63;
    int gw = blockIdx.x * 4 + wave;
    if (gw >= 3125) return;
    int quad = lane >> 4, lm = lane & 15;
    int base = gw * 16;

    floatx4 acc = (floatx4){0.f, 0.f, 0.f, 0.f};
    const float* xrow = x + (size_t)(base + lm) * 128 + quad * 8;
    unsigned short* xbrow = xbf + (size_t)(base + lm) * 128 + quad * 8;

#pragma unroll
    for (int s = 0; s < 4; ++s) {
        float4 lo = *(const float4*)(xrow + s * 32);
        float4 hi = *(const float4*)(xrow + s * 32 + 4);
        bf16x8 af;
        af[0] = (short)f2bf(lo.x); af[1] = (short)f2bf(lo.y);
        af[2] = (short)f2bf(lo.z); af[3] = (short)f2bf(lo.w);
        af[4] = (short)f2bf(hi.x); af[5] = (short)f2bf(hi.y);
        af[6] = (short)f2bf(hi.z); af[7] = (short)f2bf(hi.w);
        *(bf16x8*)(xbrow + s * 32) = af;

        bf16x8 bfv = (bf16x8){0, 0, 0, 0, 0, 0, 0, 0};
        if (lm < 8) {
            const float* bp = b + lm * 128 + s * 32 + quad * 8;
            float4 b0 = *(const float4*)bp;
            float4 b1 = *(const float4*)(bp + 4);
            bfv[0] = (short)f2bf(b0.x); bfv[1] = (short)f2bf(b0.y);
            bfv[2] = (short)f2bf(b0.z); bfv[3] = (short)f2bf(b0.w);
            bfv[4] = (short)f2bf(b1.x); bfv[5] = (short)f2bf(b1.y);
            bfv[6] = (short)f2bf(b1.z); bfv[7] = (short)f2bf(b1.w);
        }
        acc = __builtin_amdgcn_mfma_f32_16x16x32_bf16(af, bfv, acc, 0, 0, 0);
    }
    if (lm < 8) {
        float* dstp = (lm < 4) ? (s_src + (size_t)(base + quad * 4) * 4 + lm)
                               : (s_dst + (size_t)(base + quad * 4) * 4 + (lm - 4));
#pragma unroll
        for (int r = 0; r < 4; ++r) dstp[r * 4] = acc[r];
    }
}

// 3-dispatch scan: per-block sums -> scan of block sums -> per-element scan (+ bucket bases).
__global__ void k_scan_a(const int* __restrict__ counts, int* __restrict__ partial) {
    __shared__ int sm[256];
    int idx = blockIdx.x * 256 + threadIdx.x;
    sm[threadIdx.x] = (idx < N_NODES) ? counts[idx] : 0;
    __syncthreads();
    for (int s = 128; s > 0; s >>= 1) {
        if (threadIdx.x < s) sm[threadIdx.x] += sm[threadIdx.x + s];
        __syncthreads();
    }
    if (threadIdx.x == 0) partial[blockIdx.x] = sm[0];
}

__global__ void k_scan_b(const int* __restrict__ partial, int* __restrict__ chunk_off) {
    __shared__ int sm[256];
    int t = threadIdx.x;
    int v = (t < SCAN_NB) ? partial[t] : 0;
    sm[t] = v;
    __syncthreads();
    for (int s2 = 1; s2 < 256; s2 <<= 1) {
        int add = (t >= s2) ? sm[t - s2] : 0;
        __syncthreads();
        sm[t] += add;
        __syncthreads();
    }
    chunk_off[t] = sm[t] - v;   // exclusive
}

__global__ void k_scan_c(const int* __restrict__ counts, const int* __restrict__ chunk_off,
                         int* __restrict__ offsets, int* __restrict__ bcur) {
    __shared__ int sm[256];
    int t = threadIdx.x;
    int idx = blockIdx.x * 256 + t;
    int v = (idx < N_NODES) ? counts[idx] : 0;
    sm[t] = v;
    __syncthreads();
    for (int s2 = 1; s2 < 256; s2 <<= 1) {
        int add = (t >= s2) ? sm[t - s2] : 0;
        __syncthreads();
        sm[t] += add;
        __syncthreads();
    }
    if (idx < N_NODES) {
        int excl = chunk_off[blockIdx.x] + sm[t] - v;
        offsets[idx] = excl;
        if ((idx & 127) == 0) bcur[idx >> 7] = excl;   // bucket base cursor for k_binA
    }
    if (idx == 0) offsets[N_NODES] = N_EDGES;
}

// Pass A: bin packed edges (s<<16)|d into bucket regions of binned[] with contiguous per-block bursts.
__global__ __launch_bounds__(256) void k_binA(const int* __restrict__ row, const int* __restrict__ col,
        int* __restrict__ bcur, unsigned int* __restrict__ binned) {
    __shared__ int cnt[NB_BUCKET];
    __shared__ int base[NB_BUCKET];
    int t = threadIdx.x;
    for (int b = t; b < NB_BUCKET; b += 256) cnt[b] = 0;
    __syncthreads();
    unsigned int pk[BINA_EPT];
    int ebase = blockIdx.x * (256 * BINA_EPT) + t;
#pragma unroll
    for (int j = 0; j < BINA_EPT; ++j) {
        int k = ebase + j * 256;
        pk[j] = 0xffffffffu;
        if (k < N_EDGES) {
            unsigned int s = (unsigned int)row[k];
            unsigned int d = (unsigned int)col[k];
            pk[j] = (s << 16) | d;
            atomicAdd(&cnt[s >> 7], 1);
        }
    }
    __syncthreads();
    for (int b = t; b < NB_BUCKET; b += 256) {
        int c = cnt[b];
        base[b] = c ? atomicAdd(&bcur[b], c) : 0;
        cnt[b] = 0;
    }
    __syncthreads();
#pragma unroll
    for (int j = 0; j < BINA_EPT; ++j) {
        if (pk[j] != 0xffffffffu) {
            int b = pk[j] >> 23;
            int off = atomicAdd(&cnt[b], 1);
            binned[base[b] + off] = pk[j];
        }
    }
}

// Pass B: per-bucket finalize. One block owns a 128-node src range; scattered writes stay in
// this block's own output region (single-XCD L2 -> full-line writebacks). Fuses weight compute.
__global__ __launch_bounds__(256) void k_binB(const unsigned int* __restrict__ binned,
        const int* __restrict__ offsets,
        const float* __restrict__ s_src, const float* __restrict__ s_dst,
        int* __restrict__ sorted_dst, float4* __restrict__ w_sorted) {
    __shared__ int cur[128];
    int b = blockIdx.x;
    int nb = b << 7;
    int nc = min(128, N_NODES - nb);
    int t = threadIdx.x;
    if (t < nc) cur[t] = offsets[nb + t];
    __syncthreads();
    int ebeg = offsets[nb];
    int eend = offsets[nb + nc];
    for (int i = ebeg + t; i < eend; i += 256) {
        unsigned int pk = binned[i];
        int s = (int)(pk >> 16), d = (int)(pk & 0xffffu);
        float4 a4 = *(const float4*)(s_src + s * 4);
        float4 b4 = *(const float4*)(s_dst + d * 4);
        float4 w;
        w.x = lrelu_exp(a4.x + b4.x);
        w.y = lrelu_exp(a4.y + b4.y);
        w.z = lrelu_exp(a4.z + b4.z);
        w.w = lrelu_exp(a4.w + b4.w);
        int pos = atomicAdd(&cur[s - nb], 1);
        sorted_dst[pos] = d;
        w_sorted[pos] = w;
    }
}

// Per-node aggregation: bf16 x gathers (4B/lane), wave-uniform scalar loads for (dst,w4), unroll-4.
__global__ __launch_bounds__(256) void k_agg(const unsigned int* __restrict__ xb,
        const float* __restrict__ s_src, const float* __restrict__ s_dst,
        const int* __restrict__ offsets, const int* __restrict__ sorted_dst,
        const float4* __restrict__ w_sorted, const float* __restrict__ env_w,
        unsigned short* __restrict__ Gp) {
    int wave = threadIdx.x >> 6, lane = threadIdx.x & 63;
    int n = blockIdx.x * 4 + wave;
    if (n >= N_NODES) return;

    float den[4], ax[4], ay[4];

    // self loop (dst = n)
    {
        float4 sa = *(const float4*)(s_src + n * 4);
        float4 sb = *(const float4*)(s_dst + n * 4);
        float ws[4] = { lrelu_exp(sa.x + sb.x), lrelu_exp(sa.y + sb.y),
                        lrelu_exp(sa.z + sb.z), lrelu_exp(sa.w + sb.w) };
        float2 xv = bf2f(xb[(size_t)n * 64 + lane]);
#pragma unroll
        for (int e = 0; e < 4; ++e) {
            den[e] = ws[e]; ax[e] = ws[e] * xv.x; ay[e] = ws[e] * xv.y;
        }
    }

    int beg = __builtin_amdgcn_readfirstlane(offsets[n]);
    int end = __builtin_amdgcn_readfirstlane(offsets[n + 1]);
    int i = beg;
    for (; i + 3 < end; i += 4) {
        int d0 = sorted_dst[i],     d1 = sorted_dst[i + 1];
        int d2 = sorted_dst[i + 2], d3 = sorted_dst[i + 3];
        float4 w0 = w_sorted[i],     w1 = w_sorted[i + 1];
        float4 w2 = w_sorted[i + 2], w3 = w_sorted[i + 3];
        unsigned int v0 = xb[(size_t)d0 * 64 + lane];
        unsigned int v1 = xb[(size_t)d1 * 64 + lane];
        unsigned int v2 = xb[(size_t)d2 * 64 + lane];
        unsigned int v3 = xb[(size_t)d3 * 64 + lane];
        float2 x0 = bf2f(v0), x1 = bf2f(v1), x2v = bf2f(v2), x3 = bf2f(v3);
        den[0] += (w0.x + w1.x) + (w2.x + w3.x);
        den[1] += (w0.y + w1.y) + (w2.y + w3.y);
        den[2] += (w0.z + w1.z) + (w2.z + w3.z);
        den[3] += (w0.w + w1.w) + (w2.w + w3.w);
        ax[0] += w0.x * x0.x + w1.x * x1.x + w2.x * x2v.x + w3.x * x3.x;
        ay[0] += w0.x * x0.y + w1.x * x1.y + w2.x * x2v.y + w3.x * x3.y;
        ax[1] += w0.y * x0.x + w1.y * x1.x + w2.y * x2v.x + w3.y * x3.x;
        ay[1] += w0.y * x0.y + w1.y * x1.y + w2.y * x2v.y + w3.y * x3.y;
        ax[2] += w0.z * x0.x + w1.z * x1.x + w2.z * x2v.x + w3.z * x3.x;
        ay[2] += w0.z * x0.y + w1.z * x1.y + w2.z * x2v.y + w3.z * x3.y;
        ax[3] += w0.w * x0.x + w1.w * x1.x + w2.w * x2v.x + w3.w * x3.x;
        ay[3] += w0.w * x0.y + w1.w * x1.y + w2.w * x2v.y + w3.w * x3.y;
    }
    for (; i < end; ++i) {
        int d0 = sorted_dst[i];
        float4 w0 = w_sorted[i];
        float2 x0 = bf2f(xb[(size_t)d0 * 64 + lane]);
        den[0] += w0.x; den[1] += w0.y; den[2] += w0.z; den[3] += w0.w;
        ax[0] += w0.x * x0.x; ay[0] += w0.x * x0.y;
        ax[1] += w0.y * x0.x; ay[1] += w0.y * x0.y;
        ax[2] += w0.z * x0.x; ay[2] += w0.z * x0.y;
        ax[3] += w0.w * x0.x; ay[3] += w0.w * x0.y;
    }

    float4 ewt = *(const float4*)(env_w + n * 4);
    float ewv[4] = { ewt.x, ewt.y, ewt.z, ewt.w };
    unsigned int* grow = (unsigned int*)(Gp + (size_t)n * 512);
#pragma unroll
    for (int e = 0; e < 4; ++e) {
        float sc = ewv[e] / (den[e] + EPS_F);
        unsigned int lo = f2bf(sc * ax[e]);
        unsigned int hi = f2bf(sc * ay[e]);
        grow[e * 64 + lane] = (hi << 16) | lo;
    }
}

// out = G'(N x 512, bf16) @ Wcat(512 x 128, bf16 pre-swizzled) + x.  One wave = 16 rows x 128 cols.
__global__ __launch_bounds__(256) void k_gemm(const unsigned short* __restrict__ Gp,
        const unsigned short* __restrict__ Wsw,
        const float* __restrict__ x, float* __restrict__ out) {
    int wave = threadIdx.x >> 6, lane = threadIdx.x & 63;
    int gw = blockIdx.x * 4 + wave;
    if (gw >= 3125) return;
    int quad = lane >> 4, lm = lane & 15;
    int m = gw * 16 + lm;

    floatx4 acc[8];
#pragma unroll
    for (int t = 0; t < 8; ++t) acc[t] = (floatx4){0.f, 0.f, 0.f, 0.f};

    const unsigned short* Arow = Gp + (size_t)m * 512 + quad * 8;
#pragma unroll
    for (int s = 0; s < 16; ++s) {
        bf16x8 af = *(const bf16x8*)(Arow + s * 32);
#pragma unroll
        for (int t = 0; t < 8; ++t) {
            bf16x8 bfv = *(const bf16x8*)(Wsw + (((s * 8 + t) * 64 + lane) * 8));
            acc[t] = __builtin_amdgcn_mfma_f32_16x16x32_bf16(af, bfv, acc[t], 0, 0, 0);
        }
    }
    int row_base = gw * 16 + quad * 4;
#pragma unroll
    for (int t = 0; t < 8; ++t) {
        int colc = t * 16 + lm;
#pragma unroll
        for (int r = 0; r < 4; ++r) {
            int rowi = row_base + r;
            out[rowi * 128 + colc] = acc[t][r] + x[rowi * 128 + colc];
        }
    }
}

extern "C" void kernel_launch(void* const* d_in, const int* in_sizes, int n_in,
                              void* d_out, int out_size, void* d_ws, size_t ws_size,
                              hipStream_t stream) {
    const float* x       = (const float*)d_in[0];
    const int*   adj     = (const int*)d_in[1];
    const int*   row     = adj;
    const int*   col     = adj + N_EDGES;
    const float* env_w   = (const float*)d_in[2];
    const float* weights = (const float*)d_in[3];
    const float* a       = (const float*)d_in[4];
    float* out = (float*)d_out;

    char* ws = (char*)d_ws;
    size_t off = 0;
    auto alloc = [&](size_t bytes) -> char* {
        char* p = ws + off;
        off += (bytes + 255) & ~(size_t)255;
        return p;
    };
    float* b          = (float*)alloc(1024 * 4);
    float* s_src      = (float*)alloc((size_t)N_NODES * 4 * 4);
    float* s_dst      = (float*)alloc((size_t)N_NODES * 4 * 4);
    int*   counts     = (int*)alloc((size_t)N_NODES * 4);
    int*   offsets    = (int*)alloc((size_t)(N_NODES + 1) * 4);
    int*   partial    = (int*)alloc(256 * 4);
    int*   chunk_off  = (int*)alloc(256 * 4);
    int*   bcur       = (int*)alloc(512 * 4);
    unsigned int* binned = (unsigned int*)alloc((size_t)N_EDGES * 4);
    int*   sorted_dst = (int*)alloc((size_t)N_EDGES * 4);
    float4* w_sorted  = (float4*)alloc((size_t)N_EDGES * 16);
    unsigned short* wsw = (unsigned short*)alloc(65536 * 2);
    unsigned short* xbf = (unsigned short*)alloc((size_t)N_NODES * 128 * 2);
    unsigned short* Gp  = (unsigned short*)alloc((size_t)N_NODES * 512 * 2);

    hipMemsetAsync(counts, 0, (size_t)N_NODES * 4, stream);
    k_setup<<<3509, 256, 0, stream>>>(weights, a, b, wsw, row, counts);
    k_s<<<782, 256, 0, stream>>>(x, b, s_src, s_dst, xbf);
    k_scan_a<<<SCAN_NB, 256, 0, stream>>>(counts, partial);
    k_scan_b<<<1, 256, 0, stream>>>(partial, chunk_off);
    k_scan_c<<<SCAN_NB, 256, 0, stream>>>(counts, chunk_off, offsets, bcur);
    k_binA<<<196, 256, 0, stream>>>(row, col, bcur, binned);
    k_binB<<<NB_BUCKET, 256, 0, stream>>>(binned, offsets, s_src, s_dst, sorted_dst, w_sorted);
    k_agg<<<12500, 256, 0, stream>>>((const unsigned int*)xbf, s_src, s_dst, offsets, sorted_dst, w_sorted, env_w, Gp);
    k_gemm<<<782, 256, 0, stream>>>(Gp, wsw, x, out);
}